// Round 1
// baseline (232.690 us; speedup 1.0000x reference)
//
#include <hip/hip_runtime.h>

// Lovász-Softmax (B=1, C=3) — degenerate closed form.
//
// Because errors = -fg * log(p+eps) are exactly 0 for fg=0 pixels and > 0
// for fg=1 pixels, the descending sort places all fg pixels first, where the
// Lovász gradient is the constant 1/gts. The loss reduces to
//   mean over present classes c of  weight[c] * mean_{lab==c}(-log(p_c + eps))
// i.e. a masked cross-entropy mean: one memory-bound reduction pass, no sort.

#define EPS 1e-8f

__global__ __launch_bounds__(256) void lovasz_reduce_kernel(
    const float* __restrict__ probas,   // [3, P] channel-major
    const int*   __restrict__ labels,   // [3, P] one-hot int32
    float* __restrict__ acc,            // ws: [0..2]=sum_c, [3..5]=count_c
    int P4, int P)
{
    const float4* z0 = (const float4*)(probas);
    const float4* z1 = (const float4*)(probas + (size_t)P);
    const float4* z2 = (const float4*)(probas + 2 * (size_t)P);
    const int4*   l1 = (const int4*)(labels + (size_t)P);
    const int4*   l2 = (const int4*)(labels + 2 * (size_t)P);

    float s0 = 0.f, s1 = 0.f, s2 = 0.f;
    float n0 = 0.f, n1 = 0.f, n2 = 0.f;

    auto px = [&](float za, float zb, float zc, int la, int lb) {
        int lab = la + 2 * lb;                      // class id 0..2
        float m  = fmaxf(za, fmaxf(zb, zc));
        float ea = __expf(za - m);
        float eb = __expf(zb - m);
        float ec = __expf(zc - m);
        float denom = ea + eb + ec;
        float e = (lab == 0) ? ea : ((lab == 1) ? eb : ec);
        float p = e / denom;
        float err = -__logf(p + EPS);
        float f0 = (lab == 0) ? 1.f : 0.f;
        float f1 = (lab == 1) ? 1.f : 0.f;
        float f2 = (lab == 2) ? 1.f : 0.f;
        s0 += f0 * err;  s1 += f1 * err;  s2 += f2 * err;
        n0 += f0;        n1 += f1;        n2 += f2;
    };

    int stride = gridDim.x * blockDim.x;
    for (int i = blockIdx.x * blockDim.x + threadIdx.x; i < P4; i += stride) {
        float4 a = z0[i], b = z1[i], c = z2[i];
        int4   u = l1[i], v = l2[i];
        px(a.x, b.x, c.x, u.x, v.x);
        px(a.y, b.y, c.y, u.y, v.y);
        px(a.z, b.z, c.z, u.z, v.z);
        px(a.w, b.w, c.w, u.w, v.w);
    }
    // scalar tail (P not multiple of 4)
    int rem = P - P4 * 4;
    int gid = blockIdx.x * blockDim.x + threadIdx.x;
    if (gid < rem) {
        int i = P4 * 4 + gid;
        px(probas[i], probas[(size_t)P + i], probas[2 * (size_t)P + i],
           labels[(size_t)P + i], labels[2 * (size_t)P + i]);
    }

    // wave (64-lane) shuffle reduction
    for (int off = 32; off > 0; off >>= 1) {
        s0 += __shfl_down(s0, off);
        s1 += __shfl_down(s1, off);
        s2 += __shfl_down(s2, off);
        n0 += __shfl_down(n0, off);
        n1 += __shfl_down(n1, off);
        n2 += __shfl_down(n2, off);
    }

    __shared__ float red[6][4];
    int wave = threadIdx.x >> 6;
    int lane = threadIdx.x & 63;
    if (lane == 0) {
        red[0][wave] = s0; red[1][wave] = s1; red[2][wave] = s2;
        red[3][wave] = n0; red[4][wave] = n1; red[5][wave] = n2;
    }
    __syncthreads();
    if (threadIdx.x == 0) {
        #pragma unroll
        for (int k = 0; k < 6; ++k) {
            float v = red[k][0] + red[k][1] + red[k][2] + red[k][3];
            atomicAdd(&acc[k], v);
        }
    }
}

__global__ void lovasz_finalize_kernel(const float* __restrict__ acc,
                                       const float* __restrict__ weight,
                                       float* __restrict__ out)
{
    float total = 0.f, cnt = 0.f;
    #pragma unroll
    for (int c = 0; c < 3; ++c) {
        float n = acc[3 + c];
        if (n > 0.f) {
            total += weight[c] * acc[c] / n;
            cnt += 1.f;
        }
    }
    out[0] = (cnt > 0.f) ? total / fmaxf(cnt, 1.f) : 0.f;
}

extern "C" void kernel_launch(void* const* d_in, const int* in_sizes, int n_in,
                              void* d_out, int out_size, void* d_ws, size_t ws_size,
                              hipStream_t stream) {
    const float* probas = (const float*)d_in[0];
    const float* weight = (const float*)d_in[1];
    const int*   labels = (const int*)d_in[2];
    float* acc = (float*)d_ws;

    int total = in_sizes[0];        // B*C*D*H*W with B=1, C=3
    int P  = total / 3;             // pixels
    int P4 = P / 4;

    // zero the 6 accumulators (ws is poisoned 0xAA before every call)
    hipMemsetAsync(d_ws, 0, 6 * sizeof(float), stream);

    const int block = 256;
    int grid = (P4 + block - 1) / block;
    if (grid > 1024) grid = 1024;   // grid-stride; ~6 vec4 iters/thread, few atomics
    if (grid < 1) grid = 1;

    lovasz_reduce_kernel<<<grid, block, 0, stream>>>(probas, labels, acc, P4, P);
    lovasz_finalize_kernel<<<1, 1, 0, stream>>>(acc, weight, (float*)d_out);
}

// Round 2
// 166.891 us; speedup vs baseline: 1.3943x; 1.3943x over previous
//
#include <hip/hip_runtime.h>

// Lovász-Softmax (B=1, C=3) — degenerate closed form (verified R1, absmax=0):
//   loss = mean over present classes c of weight[c] * mean_{lab==c}(-log(softmax_c + 1e-8))
// One memory-bound pass. R2: full-parallelism launch (no grid-stride cap),
// 4 independent vec4 groups per thread, per-block partials in ws (no atomics,
// no memset), single finalize kernel.

#define EPS 1e-8f

__device__ __forceinline__ void px_acc(float za, float zb, float zc, int la, int lb,
                                       float& s0, float& s1, float& s2,
                                       float& n0, float& n1, float& n2)
{
    int lab = la + 2 * lb;                      // class id 0..2
    float m  = fmaxf(za, fmaxf(zb, zc));
    float ea = __expf(za - m);
    float eb = __expf(zb - m);
    float ec = __expf(zc - m);
    float denom = ea + eb + ec;
    float e = (lab == 0) ? ea : ((lab == 1) ? eb : ec);
    float p = e / denom;
    float err = -__logf(p + EPS);
    float f0 = (lab == 0) ? 1.f : 0.f;
    float f1 = (lab == 1) ? 1.f : 0.f;
    float f2 = (lab == 2) ? 1.f : 0.f;
    s0 += f0 * err;  s1 += f1 * err;  s2 += f2 * err;
    n0 += f0;        n1 += f1;        n2 += f2;
}

__global__ __launch_bounds__(256) void lovasz_reduce_kernel(
    const float* __restrict__ probas,   // [3, P] channel-major
    const int*   __restrict__ labels,   // [3, P] one-hot int32
    float* __restrict__ partial,        // ws: [6][nblocks] transposed partials
    int P4, int P, int nblocks)
{
    const float4* z0 = (const float4*)(probas);
    const float4* z1 = (const float4*)(probas + (size_t)P);
    const float4* z2 = (const float4*)(probas + 2 * (size_t)P);
    const int4*   l1 = (const int4*)(labels + (size_t)P);
    const int4*   l2 = (const int4*)(labels + 2 * (size_t)P);

    float s0 = 0.f, s1 = 0.f, s2 = 0.f;
    float n0 = 0.f, n1 = 0.f, n2 = 0.f;

    const int base = blockIdx.x * 1024 + threadIdx.x;
    #pragma unroll
    for (int j = 0; j < 4; ++j) {
        int i = base + j * 256;
        if (i < P4) {
            float4 a = z0[i], b = z1[i], c = z2[i];
            int4   u = l1[i], v = l2[i];
            px_acc(a.x, b.x, c.x, u.x, v.x, s0, s1, s2, n0, n1, n2);
            px_acc(a.y, b.y, c.y, u.y, v.y, s0, s1, s2, n0, n1, n2);
            px_acc(a.z, b.z, c.z, u.z, v.z, s0, s1, s2, n0, n1, n2);
            px_acc(a.w, b.w, c.w, u.w, v.w, s0, s1, s2, n0, n1, n2);
        }
    }

    // wave (64-lane) shuffle reduction
    #pragma unroll
    for (int off = 32; off > 0; off >>= 1) {
        s0 += __shfl_down(s0, off);
        s1 += __shfl_down(s1, off);
        s2 += __shfl_down(s2, off);
        n0 += __shfl_down(n0, off);
        n1 += __shfl_down(n1, off);
        n2 += __shfl_down(n2, off);
    }

    __shared__ float red[6][4];
    int wave = threadIdx.x >> 6;
    int lane = threadIdx.x & 63;
    if (lane == 0) {
        red[0][wave] = s0; red[1][wave] = s1; red[2][wave] = s2;
        red[3][wave] = n0; red[4][wave] = n1; red[5][wave] = n2;
    }
    __syncthreads();
    if (threadIdx.x < 6) {
        int k = threadIdx.x;
        partial[(size_t)k * nblocks + blockIdx.x] =
            red[k][0] + red[k][1] + red[k][2] + red[k][3];
    }
}

__global__ __launch_bounds__(256) void lovasz_finalize_kernel(
    const float* __restrict__ partial, int nblocks,
    const float* __restrict__ probas, const int* __restrict__ labels,
    const float* __restrict__ weight, float* __restrict__ out,
    int P4, int P)
{
    float acc[6] = {0.f, 0.f, 0.f, 0.f, 0.f, 0.f};
    for (int b = threadIdx.x; b < nblocks; b += 256) {
        #pragma unroll
        for (int k = 0; k < 6; ++k)
            acc[k] += partial[(size_t)k * nblocks + b];
    }

    #pragma unroll
    for (int k = 0; k < 6; ++k)
        #pragma unroll
        for (int off = 32; off > 0; off >>= 1)
            acc[k] += __shfl_down(acc[k], off);

    __shared__ float red[6][4];
    int wave = threadIdx.x >> 6;
    int lane = threadIdx.x & 63;
    if (lane == 0) {
        #pragma unroll
        for (int k = 0; k < 6; ++k) red[k][wave] = acc[k];
    }
    __syncthreads();
    if (threadIdx.x == 0) {
        float s[6];
        #pragma unroll
        for (int k = 0; k < 6; ++k)
            s[k] = red[k][0] + red[k][1] + red[k][2] + red[k][3];
        // scalar tail (P % 4 != 0 case; exact fit for this shape)
        for (int i = 4 * P4; i < P; ++i) {
            px_acc(probas[i], probas[(size_t)P + i], probas[2 * (size_t)P + i],
                   labels[(size_t)P + i], labels[2 * (size_t)P + i],
                   s[0], s[1], s[2], s[3], s[4], s[5]);
        }
        float total = 0.f, cnt = 0.f;
        #pragma unroll
        for (int c = 0; c < 3; ++c) {
            if (s[3 + c] > 0.f) {
                total += weight[c] * s[c] / s[3 + c];
                cnt += 1.f;
            }
        }
        out[0] = (cnt > 0.f) ? total / cnt : 0.f;
    }
}

extern "C" void kernel_launch(void* const* d_in, const int* in_sizes, int n_in,
                              void* d_out, int out_size, void* d_ws, size_t ws_size,
                              hipStream_t stream) {
    const float* probas = (const float*)d_in[0];
    const float* weight = (const float*)d_in[1];
    const int*   labels = (const int*)d_in[2];
    float* partial = (float*)d_ws;

    int total = in_sizes[0];        // B*C*D*H*W with B=1, C=3
    int P  = total / 3;             // pixels = 6,291,456
    int P4 = P / 4;                 // 1,572,864 float4 groups
    int nblocks = (P4 + 1023) / 1024;   // 1536 — exact fit, 6 blocks/CU

    lovasz_reduce_kernel<<<nblocks, 256, 0, stream>>>(probas, labels, partial,
                                                      P4, P, nblocks);
    lovasz_finalize_kernel<<<1, 256, 0, stream>>>(partial, nblocks, probas,
                                                  labels, weight, (float*)d_out,
                                                  P4, P);
}

// Round 3
// 166.796 us; speedup vs baseline: 1.3951x; 1.0006x over previous
//
#include <hip/hip_runtime.h>

// Lovász-Softmax (B=1, C=3) — degenerate closed form (verified R1/R2, absmax=0):
//   loss = mean over present classes c of weight[c] * mean_{lab==c}(-log(softmax_c + 1e-8))
// One memory-bound pass. R3: branch-free hot path (unguarded full blocks,
// guarded tail block), 3 independent vec4 groups/thread, 8 blocks/CU for
// full 32-wave occupancy. Per-block partials in ws, single finalize kernel.

#define EPS 1e-8f
#define GPT 3          // float4 groups per thread
#define BLK 256        // threads per block
#define GPB (GPT*BLK)  // groups per block = 768

__device__ __forceinline__ void px_acc(float za, float zb, float zc, int la, int lb,
                                       float& s0, float& s1, float& s2,
                                       float& n0, float& n1, float& n2)
{
    int lab = la + 2 * lb;                      // class id 0..2
    float m  = fmaxf(za, fmaxf(zb, zc));
    float ea = __expf(za - m);
    float eb = __expf(zb - m);
    float ec = __expf(zc - m);
    float denom = ea + eb + ec;
    float e = (lab == 0) ? ea : ((lab == 1) ? eb : ec);
    float p = e / denom;
    float err = -__logf(p + EPS);
    float f0 = (lab == 0) ? 1.f : 0.f;
    float f1 = (lab == 1) ? 1.f : 0.f;
    float f2 = (lab == 2) ? 1.f : 0.f;
    s0 += f0 * err;  s1 += f1 * err;  s2 += f2 * err;
    n0 += f0;        n1 += f1;        n2 += f2;
}

__global__ __launch_bounds__(BLK) void lovasz_reduce_kernel(
    const float* __restrict__ probas,   // [3, P] channel-major
    const int*   __restrict__ labels,   // [3, P] one-hot int32
    float* __restrict__ partial,        // ws: [6][nblocks] transposed partials
    int P4, int P, int nfull, int nblocks)
{
    const float4* z0 = (const float4*)(probas);
    const float4* z1 = (const float4*)(probas + (size_t)P);
    const float4* z2 = (const float4*)(probas + 2 * (size_t)P);
    const int4*   l1 = (const int4*)(labels + (size_t)P);
    const int4*   l2 = (const int4*)(labels + 2 * (size_t)P);

    float s0 = 0.f, s1 = 0.f, s2 = 0.f;
    float n0 = 0.f, n1 = 0.f, n2 = 0.f;

    const int base = blockIdx.x * GPB + threadIdx.x;

    if (blockIdx.x < nfull) {
        // hot path: no bounds checks — all 5*GPT loads issue back-to-back
        float4 a[GPT], b[GPT], c[GPT];
        int4   u[GPT], v[GPT];
        #pragma unroll
        for (int j = 0; j < GPT; ++j) {
            int i = base + j * BLK;
            a[j] = z0[i]; b[j] = z1[i]; c[j] = z2[i];
            u[j] = l1[i]; v[j] = l2[i];
        }
        #pragma unroll
        for (int j = 0; j < GPT; ++j) {
            px_acc(a[j].x, b[j].x, c[j].x, u[j].x, v[j].x, s0, s1, s2, n0, n1, n2);
            px_acc(a[j].y, b[j].y, c[j].y, u[j].y, v[j].y, s0, s1, s2, n0, n1, n2);
            px_acc(a[j].z, b[j].z, c[j].z, u[j].z, v[j].z, s0, s1, s2, n0, n1, n2);
            px_acc(a[j].w, b[j].w, c[j].w, u[j].w, v[j].w, s0, s1, s2, n0, n1, n2);
        }
    } else {
        // tail block: guarded
        #pragma unroll
        for (int j = 0; j < GPT; ++j) {
            int i = base + j * BLK;
            if (i < P4) {
                float4 a = z0[i], b = z1[i], c = z2[i];
                int4   u = l1[i], v = l2[i];
                px_acc(a.x, b.x, c.x, u.x, v.x, s0, s1, s2, n0, n1, n2);
                px_acc(a.y, b.y, c.y, u.y, v.y, s0, s1, s2, n0, n1, n2);
                px_acc(a.z, b.z, c.z, u.z, v.z, s0, s1, s2, n0, n1, n2);
                px_acc(a.w, b.w, c.w, u.w, v.w, s0, s1, s2, n0, n1, n2);
            }
        }
    }

    // wave (64-lane) shuffle reduction
    #pragma unroll
    for (int off = 32; off > 0; off >>= 1) {
        s0 += __shfl_down(s0, off);
        s1 += __shfl_down(s1, off);
        s2 += __shfl_down(s2, off);
        n0 += __shfl_down(n0, off);
        n1 += __shfl_down(n1, off);
        n2 += __shfl_down(n2, off);
    }

    __shared__ float red[6][4];
    int wave = threadIdx.x >> 6;
    int lane = threadIdx.x & 63;
    if (lane == 0) {
        red[0][wave] = s0; red[1][wave] = s1; red[2][wave] = s2;
        red[3][wave] = n0; red[4][wave] = n1; red[5][wave] = n2;
    }
    __syncthreads();
    if (threadIdx.x < 6) {
        int k = threadIdx.x;
        partial[(size_t)k * nblocks + blockIdx.x] =
            red[k][0] + red[k][1] + red[k][2] + red[k][3];
    }
}

__global__ __launch_bounds__(256) void lovasz_finalize_kernel(
    const float* __restrict__ partial, int nblocks,
    const float* __restrict__ probas, const int* __restrict__ labels,
    const float* __restrict__ weight, float* __restrict__ out,
    int P4, int P)
{
    float acc[6] = {0.f, 0.f, 0.f, 0.f, 0.f, 0.f};
    for (int b = threadIdx.x; b < nblocks; b += 256) {
        #pragma unroll
        for (int k = 0; k < 6; ++k)
            acc[k] += partial[(size_t)k * nblocks + b];
    }

    #pragma unroll
    for (int k = 0; k < 6; ++k)
        #pragma unroll
        for (int off = 32; off > 0; off >>= 1)
            acc[k] += __shfl_down(acc[k], off);

    __shared__ float red[6][4];
    int wave = threadIdx.x >> 6;
    int lane = threadIdx.x & 63;
    if (lane == 0) {
        #pragma unroll
        for (int k = 0; k < 6; ++k) red[k][wave] = acc[k];
    }
    __syncthreads();
    if (threadIdx.x == 0) {
        float s[6];
        #pragma unroll
        for (int k = 0; k < 6; ++k)
            s[k] = red[k][0] + red[k][1] + red[k][2] + red[k][3];
        // scalar tail (P % 4 != 0; empty for this shape)
        for (int i = 4 * P4; i < P; ++i) {
            px_acc(probas[i], probas[(size_t)P + i], probas[2 * (size_t)P + i],
                   labels[(size_t)P + i], labels[2 * (size_t)P + i],
                   s[0], s[1], s[2], s[3], s[4], s[5]);
        }
        float total = 0.f, cnt = 0.f;
        #pragma unroll
        for (int c = 0; c < 3; ++c) {
            if (s[3 + c] > 0.f) {
                total += weight[c] * s[c] / s[3 + c];
                cnt += 1.f;
            }
        }
        out[0] = (cnt > 0.f) ? total / cnt : 0.f;
    }
}

extern "C" void kernel_launch(void* const* d_in, const int* in_sizes, int n_in,
                              void* d_out, int out_size, void* d_ws, size_t ws_size,
                              hipStream_t stream) {
    const float* probas = (const float*)d_in[0];
    const float* weight = (const float*)d_in[1];
    const int*   labels = (const int*)d_in[2];
    float* partial = (float*)d_ws;

    int total = in_sizes[0];        // B*C*D*H*W with B=1, C=3
    int P  = total / 3;             // pixels = 6,291,456
    int P4 = P / 4;                 // 1,572,864 float4 groups
    int nfull = P4 / GPB;           // 2048 fully-covered blocks (8/CU)
    int rem = P4 - nfull * GPB;
    int nblocks = nfull + (rem ? 1 : 0);

    lovasz_reduce_kernel<<<nblocks, BLK, 0, stream>>>(probas, labels, partial,
                                                      P4, P, nfull, nblocks);
    lovasz_finalize_kernel<<<1, 256, 0, stream>>>(partial, nblocks, probas,
                                                  labels, weight, (float*)d_out,
                                                  P4, P);
}

// Round 4
// 165.877 us; speedup vs baseline: 1.4028x; 1.0055x over previous
//
#include <hip/hip_runtime.h>

// Lovász-Softmax (B=1, C=3) — degenerate closed form (verified R1–R3, absmax=0):
//   loss = mean over present classes c of weight[c] * mean_{lab==c}(-log(softmax_c + 1e-8))
// One memory-bound pass. R4: software-pipelined loop (1-deep prefetch) so each
// wave keeps loads in flight while computing — breaks the device-wide
// lockstep "load burst → compute lull" phasing of the single-shot R3 kernel.
// Grid 2048 = 8 blocks/CU, 3 loop iterations/thread (exact fit).

#define EPS 1e-8f
#define BLK 256

__device__ __forceinline__ void px_acc(float za, float zb, float zc, int la, int lb,
                                       float& s0, float& s1, float& s2,
                                       float& n0, float& n1, float& n2)
{
    int lab = la + 2 * lb;                      // class id 0..2
    float m  = fmaxf(za, fmaxf(zb, zc));
    float ea = __expf(za - m);
    float eb = __expf(zb - m);
    float ec = __expf(zc - m);
    float denom = ea + eb + ec;
    float e = (lab == 0) ? ea : ((lab == 1) ? eb : ec);
    float p = e / denom;
    float err = -__logf(p + EPS);
    float f0 = (lab == 0) ? 1.f : 0.f;
    float f1 = (lab == 1) ? 1.f : 0.f;
    float f2 = (lab == 2) ? 1.f : 0.f;
    s0 += f0 * err;  s1 += f1 * err;  s2 += f2 * err;
    n0 += f0;        n1 += f1;        n2 += f2;
}

__device__ __forceinline__ void px4(const float4& a, const float4& b, const float4& c,
                                    const int4& u, const int4& v,
                                    float& s0, float& s1, float& s2,
                                    float& n0, float& n1, float& n2)
{
    px_acc(a.x, b.x, c.x, u.x, v.x, s0, s1, s2, n0, n1, n2);
    px_acc(a.y, b.y, c.y, u.y, v.y, s0, s1, s2, n0, n1, n2);
    px_acc(a.z, b.z, c.z, u.z, v.z, s0, s1, s2, n0, n1, n2);
    px_acc(a.w, b.w, c.w, u.w, v.w, s0, s1, s2, n0, n1, n2);
}

__global__ __launch_bounds__(BLK) void lovasz_reduce_kernel(
    const float* __restrict__ probas,   // [3, P] channel-major
    const int*   __restrict__ labels,   // [3, P] one-hot int32
    float* __restrict__ partial,        // ws: [6][nblocks] transposed partials
    int P4, int P, int niter, int nblocks)
{
    const float4* z0 = (const float4*)(probas);
    const float4* z1 = (const float4*)(probas + (size_t)P);
    const float4* z2 = (const float4*)(probas + 2 * (size_t)P);
    const int4*   l1 = (const int4*)(labels + (size_t)P);
    const int4*   l2 = (const int4*)(labels + 2 * (size_t)P);

    float s0 = 0.f, s1 = 0.f, s2 = 0.f;
    float n0 = 0.f, n1 = 0.f, n2 = 0.f;

    const int tid    = blockIdx.x * BLK + threadIdx.x;
    const int stride = nblocks * BLK;

    if (niter > 0) {
        int i = tid;
        // prefetch iteration 0
        float4 a0 = z0[i], b0 = z1[i], c0 = z2[i];
        int4   u0 = l1[i], v0 = l2[i];
        for (int it = 1; it < niter; ++it) {
            int inext = i + stride;
            // issue next iteration's 5 loads BEFORE computing on current —
            // compiler emits them, then waits only on the current regs
            float4 a1 = z0[inext], b1 = z1[inext], c1 = z2[inext];
            int4   u1 = l1[inext], v1 = l2[inext];
            px4(a0, b0, c0, u0, v0, s0, s1, s2, n0, n1, n2);
            a0 = a1; b0 = b1; c0 = c1; u0 = u1; v0 = v1;
            i = inext;
        }
        px4(a0, b0, c0, u0, v0, s0, s1, s2, n0, n1, n2);
    }

    // guarded tail groups beyond niter*stride
    {
        int i = niter * stride + tid;
        if (i < P4) {
            float4 a = z0[i], b = z1[i], c = z2[i];
            int4   u = l1[i], v = l2[i];
            px4(a, b, c, u, v, s0, s1, s2, n0, n1, n2);
        }
    }

    // wave (64-lane) shuffle reduction
    #pragma unroll
    for (int off = 32; off > 0; off >>= 1) {
        s0 += __shfl_down(s0, off);
        s1 += __shfl_down(s1, off);
        s2 += __shfl_down(s2, off);
        n0 += __shfl_down(n0, off);
        n1 += __shfl_down(n1, off);
        n2 += __shfl_down(n2, off);
    }

    __shared__ float red[6][4];
    int wave = threadIdx.x >> 6;
    int lane = threadIdx.x & 63;
    if (lane == 0) {
        red[0][wave] = s0; red[1][wave] = s1; red[2][wave] = s2;
        red[3][wave] = n0; red[4][wave] = n1; red[5][wave] = n2;
    }
    __syncthreads();
    if (threadIdx.x < 6) {
        int k = threadIdx.x;
        partial[(size_t)k * nblocks + blockIdx.x] =
            red[k][0] + red[k][1] + red[k][2] + red[k][3];
    }
}

__global__ __launch_bounds__(256) void lovasz_finalize_kernel(
    const float* __restrict__ partial, int nblocks,
    const float* __restrict__ probas, const int* __restrict__ labels,
    const float* __restrict__ weight, float* __restrict__ out,
    int P4, int P)
{
    float acc[6] = {0.f, 0.f, 0.f, 0.f, 0.f, 0.f};
    for (int b = threadIdx.x; b < nblocks; b += 256) {
        #pragma unroll
        for (int k = 0; k < 6; ++k)
            acc[k] += partial[(size_t)k * nblocks + b];
    }

    #pragma unroll
    for (int k = 0; k < 6; ++k)
        #pragma unroll
        for (int off = 32; off > 0; off >>= 1)
            acc[k] += __shfl_down(acc[k], off);

    __shared__ float red[6][4];
    int wave = threadIdx.x >> 6;
    int lane = threadIdx.x & 63;
    if (lane == 0) {
        #pragma unroll
        for (int k = 0; k < 6; ++k) red[k][wave] = acc[k];
    }
    __syncthreads();
    if (threadIdx.x == 0) {
        float s[6];
        #pragma unroll
        for (int k = 0; k < 6; ++k)
            s[k] = red[k][0] + red[k][1] + red[k][2] + red[k][3];
        // scalar tail (P % 4 != 0; empty for this shape)
        for (int i = 4 * P4; i < P; ++i) {
            px_acc(probas[i], probas[(size_t)P + i], probas[2 * (size_t)P + i],
                   labels[(size_t)P + i], labels[2 * (size_t)P + i],
                   s[0], s[1], s[2], s[3], s[4], s[5]);
        }
        float total = 0.f, cnt = 0.f;
        #pragma unroll
        for (int c = 0; c < 3; ++c) {
            if (s[3 + c] > 0.f) {
                total += weight[c] * s[c] / s[3 + c];
                cnt += 1.f;
            }
        }
        out[0] = (cnt > 0.f) ? total / cnt : 0.f;
    }
}

extern "C" void kernel_launch(void* const* d_in, const int* in_sizes, int n_in,
                              void* d_out, int out_size, void* d_ws, size_t ws_size,
                              hipStream_t stream) {
    const float* probas = (const float*)d_in[0];
    const float* weight = (const float*)d_in[1];
    const int*   labels = (const int*)d_in[2];
    float* partial = (float*)d_ws;

    int total = in_sizes[0];        // B*C*D*H*W with B=1, C=3
    int P  = total / 3;             // pixels = 6,291,456
    int P4 = P / 4;                 // 1,572,864 float4 groups

    const int nblocks = 2048;       // 8 blocks/CU, full 32-wave residency
    int stride = nblocks * BLK;     // 524,288
    int niter  = P4 / stride;       // 3 for this shape (exact fit)

    lovasz_reduce_kernel<<<nblocks, BLK, 0, stream>>>(probas, labels, partial,
                                                      P4, P, niter, nblocks);
    lovasz_finalize_kernel<<<1, 256, 0, stream>>>(partial, nblocks, probas,
                                                  labels, weight, (float*)d_out,
                                                  P4, P);
}